// Round 1
// baseline (12223.295 us; speedup 1.0000x reference)
//
#include <hip/hip_runtime.h>
#include <hip/hip_bf16.h>

#define T    48
#define I0   34
#define H    68
#define G    272   // 4*H
#define I1   136   // 2*H
#define BT   4     // batch tile per block
#define NTHR 320   // 5 waves
#define B_ALL 16384

struct __align__(16) Smem {
  __hip_bfloat16 h0[BT][T][2 * H];  // 52224 B  layer-0 output sequence (bf16)
  float gates[BT][G];               //  4352 B
  float hst[BT][H];                 //  1088 B
  float cst[BT][H];                 //  1088 B
  float xbuf[BT][36];               //   576 B  (rows padded 34->36 for 16B alignment)
  float yacc[BT][5];                //    80 B
};                                  // total 59408 B static LDS

__device__ __forceinline__ float sigm(float x)  { return 1.0f / (1.0f + __expf(-x)); }
__device__ __forceinline__ float tanhf_(float x){ return 2.0f / (1.0f + __expf(-2.0f * x)) - 1.0f; }
__device__ __forceinline__ float bflo(unsigned u){ return __uint_as_float(u << 16); }
__device__ __forceinline__ float bfhi(unsigned u){ return __uint_as_float(u & 0xffff0000u); }

template<int IN, bool IS_L1>
__device__ __forceinline__ void run_phase(Smem& s,
    const float* __restrict__ Wih, const float* __restrict__ Whh,
    const float* __restrict__ bih, const float* __restrict__ bhh,
    const float* __restrict__ xg,  const float* __restrict__ fcw,
    const int dir, const int tid)
{
  // --- per-thread weight rows in registers (fully unrolled, constant-indexed) ---
  float wih[IN];
  float whh[H];
  float bias = 0.0f;
  if (tid < G) {
    #pragma unroll
    for (int i = 0; i < IN; ++i) wih[i] = Wih[tid * IN + i];
    #pragma unroll
    for (int j = 0; j < H; ++j)  whh[j] = Whh[tid * H + j];
    bias = bih[tid] + bhh[tid];
  }
  if (tid < BT * H) {
    s.hst[tid / H][tid % H] = 0.0f;
    s.cst[tid / H][tid % H] = 0.0f;
  }
  __syncthreads();

  for (int st = 0; st < T; ++st) {
    const int t = dir ? (T - 1 - st) : st;

    if constexpr (!IS_L1) {
      if (tid < BT * I0) {
        const int b = tid / I0, i = tid - b * I0;
        s.xbuf[b][i] = xg[(size_t)b * (T * I0) + t * I0 + i];
      }
      __syncthreads();
    }

    // --- gate compute: thread g owns gate row g, 4 batch accumulators ---
    if (tid < G) {
      float acc0 = bias, acc1 = bias, acc2 = bias, acc3 = bias;
      if constexpr (IS_L1) {
        #pragma unroll
        for (int c = 0; c < 17; ++c) {
          const uint4 v0 = *(const uint4*)&s.h0[0][t][c * 8];
          const uint4 v1 = *(const uint4*)&s.h0[1][t][c * 8];
          const uint4 v2 = *(const uint4*)&s.h0[2][t][c * 8];
          const uint4 v3 = *(const uint4*)&s.h0[3][t][c * 8];
          const float w0 = wih[c*8+0], w1 = wih[c*8+1], w2 = wih[c*8+2], w3 = wih[c*8+3];
          const float w4 = wih[c*8+4], w5 = wih[c*8+5], w6 = wih[c*8+6], w7 = wih[c*8+7];
          acc0 += w0*bflo(v0.x) + w1*bfhi(v0.x) + w2*bflo(v0.y) + w3*bfhi(v0.y)
                + w4*bflo(v0.z) + w5*bfhi(v0.z) + w6*bflo(v0.w) + w7*bfhi(v0.w);
          acc1 += w0*bflo(v1.x) + w1*bfhi(v1.x) + w2*bflo(v1.y) + w3*bfhi(v1.y)
                + w4*bflo(v1.z) + w5*bfhi(v1.z) + w6*bflo(v1.w) + w7*bfhi(v1.w);
          acc2 += w0*bflo(v2.x) + w1*bfhi(v2.x) + w2*bflo(v2.y) + w3*bfhi(v2.y)
                + w4*bflo(v2.z) + w5*bfhi(v2.z) + w6*bflo(v2.w) + w7*bfhi(v2.w);
          acc3 += w0*bflo(v3.x) + w1*bfhi(v3.x) + w2*bflo(v3.y) + w3*bfhi(v3.y)
                + w4*bflo(v3.z) + w5*bfhi(v3.z) + w6*bflo(v3.w) + w7*bfhi(v3.w);
        }
      } else {
        #pragma unroll
        for (int c = 0; c < 8; ++c) {
          const float4 v0 = *(const float4*)&s.xbuf[0][c * 4];
          const float4 v1 = *(const float4*)&s.xbuf[1][c * 4];
          const float4 v2 = *(const float4*)&s.xbuf[2][c * 4];
          const float4 v3 = *(const float4*)&s.xbuf[3][c * 4];
          const float w0 = wih[c*4+0], w1 = wih[c*4+1], w2 = wih[c*4+2], w3 = wih[c*4+3];
          acc0 += w0*v0.x + w1*v0.y + w2*v0.z + w3*v0.w;
          acc1 += w0*v1.x + w1*v1.y + w2*v1.z + w3*v1.w;
          acc2 += w0*v2.x + w1*v2.y + w2*v2.z + w3*v2.w;
          acc3 += w0*v3.x + w1*v3.y + w2*v3.z + w3*v3.w;
        }
        acc0 += wih[32]*s.xbuf[0][32] + wih[33]*s.xbuf[0][33];
        acc1 += wih[32]*s.xbuf[1][32] + wih[33]*s.xbuf[1][33];
        acc2 += wih[32]*s.xbuf[2][32] + wih[33]*s.xbuf[2][33];
        acc3 += wih[32]*s.xbuf[3][32] + wih[33]*s.xbuf[3][33];
      }
      // recurrent part
      #pragma unroll
      for (int c = 0; c < 17; ++c) {
        const float4 u0 = *(const float4*)&s.hst[0][c * 4];
        const float4 u1 = *(const float4*)&s.hst[1][c * 4];
        const float4 u2 = *(const float4*)&s.hst[2][c * 4];
        const float4 u3 = *(const float4*)&s.hst[3][c * 4];
        const float w0 = whh[c*4+0], w1 = whh[c*4+1], w2 = whh[c*4+2], w3 = whh[c*4+3];
        acc0 += w0*u0.x + w1*u0.y + w2*u0.z + w3*u0.w;
        acc1 += w0*u1.x + w1*u1.y + w2*u1.z + w3*u1.w;
        acc2 += w0*u2.x + w1*u2.y + w2*u2.z + w3*u2.w;
        acc3 += w0*u3.x + w1*u3.y + w2*u3.z + w3*u3.w;
      }
      s.gates[0][tid] = acc0;
      s.gates[1][tid] = acc1;
      s.gates[2][tid] = acc2;
      s.gates[3][tid] = acc3;
    }
    __syncthreads();

    // --- elementwise cell/hidden update: one thread per (b, j) ---
    if (tid < BT * H) {
      const int b = tid / H, j = tid - b * H;
      const float ig = sigm(s.gates[b][j]);
      const float fg = sigm(s.gates[b][H + j]);
      const float gg = tanhf_(s.gates[b][2 * H + j]);
      const float og = sigm(s.gates[b][3 * H + j]);
      const float c  = fg * s.cst[b][j] + ig * gg;
      s.cst[b][j] = c;
      const float h = og * tanhf_(c);
      s.hst[b][j] = h;
      if constexpr (!IS_L1) s.h0[b][t][dir * H + j] = __float2bfloat16(h);
    }
    __syncthreads();

    // --- FC accumulation (layer 1 only): y[b][k] += h1_t . fc_w[k, t*136 + dir*68 : +68] ---
    if constexpr (IS_L1) {
      if (tid < BT * 5) {
        const int b = tid / 5, k = tid - b * 5;
        const float* __restrict__ w = fcw + (size_t)k * (T * 2 * H) + t * (2 * H) + dir * H;
        float a0 = 0.f, a1 = 0.f, a2 = 0.f, a3 = 0.f;
        #pragma unroll
        for (int j = 0; j < H; j += 4) {
          a0 += s.hst[b][j + 0] * w[j + 0];
          a1 += s.hst[b][j + 1] * w[j + 1];
          a2 += s.hst[b][j + 2] * w[j + 2];
          a3 += s.hst[b][j + 3] * w[j + 3];
        }
        s.yacc[b][k] += (a0 + a1) + (a2 + a3);
      }
      // no barrier needed: next write to hst is after the next gate barrier
    }
  }
}

__global__ __launch_bounds__(NTHR, 2)
void lstm_fc_kernel(const float* __restrict__ x,
                    const float* __restrict__ Wih0f, const float* __restrict__ Whh0f,
                    const float* __restrict__ bih0f, const float* __restrict__ bhh0f,
                    const float* __restrict__ Wih0b, const float* __restrict__ Whh0b,
                    const float* __restrict__ bih0b, const float* __restrict__ bhh0b,
                    const float* __restrict__ Wih1f, const float* __restrict__ Whh1f,
                    const float* __restrict__ bih1f, const float* __restrict__ bhh1f,
                    const float* __restrict__ Wih1b, const float* __restrict__ Whh1b,
                    const float* __restrict__ bih1b, const float* __restrict__ bhh1b,
                    const float* __restrict__ fcw,   const float* __restrict__ fcb,
                    float* __restrict__ out)
{
  __shared__ Smem s;
  const int tid = threadIdx.x;
  const float* xg = x + (size_t)blockIdx.x * BT * (T * I0);

  run_phase<I0, false>(s, Wih0f, Whh0f, bih0f, bhh0f, xg, nullptr, 0, tid);
  __syncthreads();
  run_phase<I0, false>(s, Wih0b, Whh0b, bih0b, bhh0b, xg, nullptr, 1, tid);
  __syncthreads();
  if (tid < BT * 5) s.yacc[tid / 5][tid % 5] = 0.0f;
  __syncthreads();
  run_phase<I1, true>(s, Wih1f, Whh1f, bih1f, bhh1f, nullptr, fcw, 0, tid);
  __syncthreads();
  run_phase<I1, true>(s, Wih1b, Whh1b, bih1b, bhh1b, nullptr, fcw, 1, tid);
  __syncthreads();

  if (tid < BT * 5) {
    const int b = tid / 5, k = tid - b * 5;
    out[((size_t)blockIdx.x * BT + b) * 5 + k] = s.yacc[b][k] + fcb[k];
  }
}

extern "C" void kernel_launch(void* const* d_in, const int* in_sizes, int n_in,
                              void* d_out, int out_size, void* d_ws, size_t ws_size,
                              hipStream_t stream) {
  (void)in_sizes; (void)n_in; (void)d_ws; (void)ws_size; (void)out_size;
  const float* x     = (const float*)d_in[0];
  const float* Wih0f = (const float*)d_in[1];
  const float* Whh0f = (const float*)d_in[2];
  const float* bih0f = (const float*)d_in[3];
  const float* bhh0f = (const float*)d_in[4];
  const float* Wih0b = (const float*)d_in[5];
  const float* Whh0b = (const float*)d_in[6];
  const float* bih0b = (const float*)d_in[7];
  const float* bhh0b = (const float*)d_in[8];
  const float* Wih1f = (const float*)d_in[9];
  const float* Whh1f = (const float*)d_in[10];
  const float* bih1f = (const float*)d_in[11];
  const float* bhh1f = (const float*)d_in[12];
  const float* Wih1b = (const float*)d_in[13];
  const float* Whh1b = (const float*)d_in[14];
  const float* bih1b = (const float*)d_in[15];
  const float* bhh1b = (const float*)d_in[16];
  const float* fcw   = (const float*)d_in[17];
  const float* fcb   = (const float*)d_in[18];
  float* out = (float*)d_out;

  dim3 grid(B_ALL / BT);
  dim3 block(NTHR);
  lstm_fc_kernel<<<grid, block, 0, stream>>>(x,
      Wih0f, Whh0f, bih0f, bhh0f, Wih0b, Whh0b, bih0b, bhh0b,
      Wih1f, Whh1f, bih1f, bhh1f, Wih1b, Whh1b, bih1b, bhh1b,
      fcw, fcb, out);
}

// Round 2
// 1860.709 us; speedup vs baseline: 6.5692x; 6.5692x over previous
//
#include <hip/hip_runtime.h>

typedef _Float16 half8 __attribute__((ext_vector_type(8)));
typedef float f32x4 __attribute__((ext_vector_type(4)));

#define TT 48
#define BT 8
#define NSEQ 16384
#define NBLK (NSEQ / BT)
#define NTHR 512

struct __align__(16) Smem {
  _Float16 h0[TT][BT][136];   // 104448 B  layer-0 output history (f16)
  float gates[2][272][9];     //  19584 B  gate pre-activations per dir
  _Float16 A0[2][16][136];    //   8704 B  layer-0 A panel: [x_t(34) | h(68) | pad]
  _Float16 A1[2][16][232];    //  14848 B  layer-1 A panel: [h0_t(136) | h1(68) | pad]
  float yacc[BT][5];          //    160 B
};                            // 147744 B dynamic LDS

__device__ __forceinline__ float sigm(float x) { return 1.f / (1.f + __expf(-x)); }
__device__ __forceinline__ float tanh_s(float x) {
  const float a = fabsf(x);
  const float e = __expf(-2.f * a);
  const float r = (1.f - e) / (1.f + e);   // no overflow: e <= 1
  return x < 0.f ? -r : r;
}

template <int LAYER>
__device__ __forceinline__ void phase(Smem& s,
    const float* __restrict__ Wih, const float* __restrict__ Whh,
    const float* __restrict__ bih, const float* __restrict__ bhh,
    const float* __restrict__ x, const float* __restrict__ fcw, int blk)
{
  constexpr int IN = (LAYER == 0) ? 34 : 136;   // non-recurrent input width
  constexpr int KS = (LAYER == 0) ? 4 : 7;      // K-steps of 32 (K = 128 / 224)
  constexpr int AW = (LAYER == 0) ? 136 : 232;  // A panel row stride (f16 elems)
  const int tid = threadIdx.x;
  const int ln = tid & 63;
  const int wid = tid >> 6;
  const int d = wid >> 2;        // 0 = fwd (waves 0-3), 1 = bwd (waves 4-7)
  const int wq = wid & 3;
  const int ut = tid & 255;      // lane id within direction group
  const int NT = (wq == 0) ? 5 : 4;                 // N-tiles owned (17 total)
  const int tbase = (wq == 0) ? 0 : (1 + wq * 4);   // w0:0-4 w1:5-8 w2:9-12 w3:13-16
  _Float16* Abuf = (LAYER == 0) ? &s.A0[d][0][0] : &s.A1[d][0][0];

  // ---- B fragments: held in registers for all 48 steps ----
  // B[k][n]: col n = lane%16, k = (lane/16)*8 + j.  k<IN -> Wih, k<IN+68 -> Whh, else 0.
  half8 Bf[5][KS];
  #pragma unroll
  for (int i = 0; i < 5; ++i) {
    if (i < NT) {
      const int g = (tbase + i) * 16 + (ln & 15);
      #pragma unroll
      for (int kk = 0; kk < KS; ++kk) {
        const int k0 = kk * 32 + (ln >> 4) * 8;
        half8 v;
        #pragma unroll
        for (int j = 0; j < 8; ++j) {
          const int k = k0 + j;
          float w = 0.f;
          if (k < IN) w = Wih[g * IN + k];
          else if (k < IN + 68) w = Whh[g * 68 + (k - IN)];
          v[j] = (_Float16)w;
        }
        Bf[i][kk] = v;
      }
    }
  }

  // ---- per-lane (b,j) ownership: p = j*8+b; lane owns p = ut, ut+256, ut+512(ut<32) ----
  const int jb = ut >> 3, bb = ut & 7;
  float bsI[3], bsF[3], bsG[3], bsO[3];
  #pragma unroll
  for (int q = 0; q < 3; ++q) {
    if (q < 2 || ut < 32) {
      const int j = jb + 32 * q;
      bsI[q] = bih[j] + bhh[j];
      bsF[q] = bih[68 + j] + bhh[68 + j];
      bsG[q] = bih[136 + j] + bhh[136 + j];
      bsO[q] = bih[204 + j] + bhh[204 + j];
    }
  }
  float cst[3] = {0.f, 0.f, 0.f};
  float yk[3][5];
  #pragma unroll
  for (int q = 0; q < 3; ++q)
    #pragma unroll
    for (int k = 0; k < 5; ++k) yk[q][k] = 0.f;

  const int t0 = d ? (TT - 1) : 0;

  // ---- prologue: stage step-0 inputs into the A panel ----
  if constexpr (LAYER == 0) {
    {
      const int b = ut / 34, i = ut % 34;
      s.A0[d][b][i] = (_Float16)x[((size_t)(blk * BT + b) * TT + t0) * 34 + i];
    }
    if (ut < 16) {
      const int e = ut + 256, b = e / 34, i = e % 34;
      s.A0[d][b][i] = (_Float16)x[((size_t)(blk * BT + b) * TT + t0) * 34 + i];
    }
  } else {
    if (ut < 136) {
      const int b = ut / 17, ch = ut % 17;
      *(uint4*)&s.A1[d][b][ch * 8] = *(const uint4*)&s.h0[t0][b][ch * 8];
    }
  }
  __syncthreads();

  #pragma unroll 1
  for (int st = 0; st < TT; ++st) {
    const int t = d ? (TT - 1 - st) : st;
    const int tn = d ? (t - 1) : (t + 1);

    // ---- issue prefetches: next-step x (L0) / this-step fcw slice (L1) ----
    float xpf0 = 0.f, xpf1 = 0.f;
    if constexpr (LAYER == 0) {
      if (st < TT - 1) {
        const int b = ut / 34, i = ut % 34;
        xpf0 = x[((size_t)(blk * BT + b) * TT + tn) * 34 + i];
        if (ut < 16) {
          const int e = ut + 256, b2 = e / 34, i2 = e % 34;
          xpf1 = x[((size_t)(blk * BT + b2) * TT + tn) * 34 + i2];
        }
      }
    }
    float fw[3][5];
    if constexpr (LAYER == 1) {
      #pragma unroll
      for (int q = 0; q < 3; ++q) {
        if (q < 2 || ut < 32) {
          const int j = jb + 32 * q;
          #pragma unroll
          for (int k = 0; k < 5; ++k)
            fw[q][k] = fcw[k * 6528 + t * 136 + d * 68 + j];
        }
      }
    }

    // ---- MFMA: gates = A(8xK) . B(Kx272) ----
    f32x4 acc[5];
    #pragma unroll
    for (int i = 0; i < 5; ++i) acc[i] = (f32x4){0.f, 0.f, 0.f, 0.f};
    const _Float16* Arow = Abuf + (ln & 15) * AW + (ln >> 4) * 8;
    #pragma unroll
    for (int kk = 0; kk < KS; ++kk) {
      const half8 a = *(const half8*)(Arow + kk * 32);
      #pragma unroll
      for (int i = 0; i < 5; ++i)
        if (i < NT)
          acc[i] = __builtin_amdgcn_mfma_f32_16x16x32_f16(a, Bf[i][kk], acc[i], 0, 0, 0);
    }
    // C/D: col = lane&15, row = (lane>>4)*4 + reg; rows 8-15 are padding
    if (ln < 32) {
      #pragma unroll
      for (int i = 0; i < 5; ++i)
        if (i < NT) {
          const int g = (tbase + i) * 16 + (ln & 15);
          #pragma unroll
          for (int r = 0; r < 4; ++r)
            s.gates[d][g][(ln >> 4) * 4 + r] = acc[i][r];
        }
    }
    __syncthreads();

    // ---- elementwise cell update (c stays in registers) ----
    #pragma unroll
    for (int q = 0; q < 3; ++q) {
      if (q < 2 || ut < 32) {
        const int j = jb + 32 * q;
        const float gi = s.gates[d][j][bb] + bsI[q];
        const float gf = s.gates[d][68 + j][bb] + bsF[q];
        const float gg = s.gates[d][136 + j][bb] + bsG[q];
        const float go = s.gates[d][204 + j][bb] + bsO[q];
        const float ii = sigm(gi), ff = sigm(gf), g2 = tanh_s(gg), oo = sigm(go);
        const float c = ff * cst[q] + ii * g2;
        cst[q] = c;
        const float h = oo * tanh_s(c);
        const _Float16 hh = (_Float16)h;
        if constexpr (LAYER == 0) {
          s.A0[d][bb][34 + j] = hh;
          s.h0[t][bb][d * 68 + j] = hh;
        } else {
          s.A1[d][bb][136 + j] = hh;
          #pragma unroll
          for (int k = 0; k < 5; ++k) yk[q][k] += h * fw[q][k];
        }
      }
    }
    // ---- stage next step's non-recurrent A part ----
    if constexpr (LAYER == 0) {
      if (st < TT - 1) {
        const int b = ut / 34, i = ut % 34;
        s.A0[d][b][i] = (_Float16)xpf0;
        if (ut < 16) {
          const int e = ut + 256, b2 = e / 34, i2 = e % 34;
          s.A0[d][b2][i2] = (_Float16)xpf1;
        }
      }
    } else {
      if (st < TT - 1 && ut < 136) {
        const int b = ut / 17, ch = ut % 17;
        *(uint4*)&s.A1[d][b][ch * 8] = *(const uint4*)&s.h0[tn][b][ch * 8];
      }
    }
    __syncthreads();
  }

  if constexpr (LAYER == 1) {
    #pragma unroll
    for (int q = 0; q < 3; ++q) {
      if (q < 2 || ut < 32) {
        #pragma unroll
        for (int k = 0; k < 5; ++k)
          atomicAdd(&s.yacc[bb][k], yk[q][k]);
      }
    }
  }
}

__global__ __launch_bounds__(NTHR, 2) void lstm_fc_mfma(
    const float* __restrict__ x,
    const float* __restrict__ Wih0f, const float* __restrict__ Whh0f,
    const float* __restrict__ bih0f, const float* __restrict__ bhh0f,
    const float* __restrict__ Wih0b, const float* __restrict__ Whh0b,
    const float* __restrict__ bih0b, const float* __restrict__ bhh0b,
    const float* __restrict__ Wih1f, const float* __restrict__ Whh1f,
    const float* __restrict__ bih1f, const float* __restrict__ bhh1f,
    const float* __restrict__ Wih1b, const float* __restrict__ Whh1b,
    const float* __restrict__ bih1b, const float* __restrict__ bhh1b,
    const float* __restrict__ fcw, const float* __restrict__ fcb,
    float* __restrict__ out)
{
  extern __shared__ char smem_raw[];
  Smem& s = *reinterpret_cast<Smem*>(smem_raw);
  const int tid = threadIdx.x;
  const int blk = blockIdx.x;
  const int d = (tid >> 8) & 1;

  // zero A0 | A1 | yacc (contiguous tail of the struct)
  {
    int* z = (int*)&s.A0[0][0][0];
    const int n = (int)((sizeof(s.A0) + sizeof(s.A1) + sizeof(s.yacc)) / 4);
    for (int i = tid; i < n; i += NTHR) z[i] = 0;
  }
  __syncthreads();

  phase<0>(s, d ? Wih0b : Wih0f, d ? Whh0b : Whh0f,
              d ? bih0b : bih0f, d ? bhh0b : bhh0f, x, nullptr, blk);
  __syncthreads();
  phase<1>(s, d ? Wih1b : Wih1f, d ? Whh1b : Whh1f,
              d ? bih1b : bih1f, d ? bhh1b : bhh1f, nullptr, fcw, blk);
  __syncthreads();

  if (tid < BT * 5) {
    const int b = tid / 5, k = tid % 5;
    out[((size_t)blk * BT + b) * 5 + k] = s.yacc[b][k] + fcb[k];
  }
}

extern "C" void kernel_launch(void* const* d_in, const int* in_sizes, int n_in,
                              void* d_out, int out_size, void* d_ws, size_t ws_size,
                              hipStream_t stream) {
  (void)in_sizes; (void)n_in; (void)d_ws; (void)ws_size; (void)out_size;
  static_assert(sizeof(Smem) <= 160 * 1024, "LDS overflow");
  hipFuncSetAttribute((const void*)lstm_fc_mfma,
                      hipFuncAttributeMaxDynamicSharedMemorySize, (int)sizeof(Smem));

  const float* x     = (const float*)d_in[0];
  const float* Wih0f = (const float*)d_in[1];
  const float* Whh0f = (const float*)d_in[2];
  const float* bih0f = (const float*)d_in[3];
  const float* bhh0f = (const float*)d_in[4];
  const float* Wih0b = (const float*)d_in[5];
  const float* Whh0b = (const float*)d_in[6];
  const float* bih0b = (const float*)d_in[7];
  const float* bhh0b = (const float*)d_in[8];
  const float* Wih1f = (const float*)d_in[9];
  const float* Whh1f = (const float*)d_in[10];
  const float* bih1f = (const float*)d_in[11];
  const float* bhh1f = (const float*)d_in[12];
  const float* Wih1b = (const float*)d_in[13];
  const float* Whh1b = (const float*)d_in[14];
  const float* bih1b = (const float*)d_in[15];
  const float* bhh1b = (const float*)d_in[16];
  const float* fcw   = (const float*)d_in[17];
  const float* fcb   = (const float*)d_in[18];
  float* out = (float*)d_out;

  lstm_fc_mfma<<<dim3(NBLK), dim3(NTHR), sizeof(Smem), stream>>>(x,
      Wih0f, Whh0f, bih0f, bhh0f, Wih0b, Whh0b, bih0b, bhh0b,
      Wih1f, Whh1f, bih1f, bhh1f, Wih1b, Whh1b, bih1b, bhh1b,
      fcw, fcb, out);
}

// Round 3
// 1447.177 us; speedup vs baseline: 8.4463x; 1.2858x over previous
//
#include <hip/hip_runtime.h>

typedef _Float16 half8 __attribute__((ext_vector_type(8)));
typedef float f32x4 __attribute__((ext_vector_type(4)));

#define TT 48
#define BT 8
#define NSEQ 16384
#define NBLK (NSEQ / BT)
#define NTHR 512

struct __align__(16) Smem {
  _Float16 h0[TT][BT][136];   // 104448 B  layer-0 output history (f16)
  float gates[2][272][9];     //  19584 B  gate pre-activations per dir
  _Float16 A0[2][16][136];    //   8704 B  layer-0 A panel: [x_t(34) | h(68) | pad]
  _Float16 A1[2][16][232];    //  14848 B  layer-1 A panel: [h0_t(136) | h1(68) | pad]
  float yred[8][8][5];        //   1280 B  per-wave FC partials
};                            // 148864 B dynamic LDS

__device__ __forceinline__ float fast_rcp(float x) { return __builtin_amdgcn_rcpf(x); }
__device__ __forceinline__ float sigm(float x)  { return fast_rcp(1.f + __expf(-x)); }
__device__ __forceinline__ float tanh_s(float x){ return 1.f - 2.f * fast_rcp(1.f + __expf(2.f * x)); }

template <int LAYER>
__device__ __forceinline__ void phase(Smem& s,
    const float* __restrict__ Wih, const float* __restrict__ Whh,
    const float* __restrict__ bih, const float* __restrict__ bhh,
    const float* __restrict__ x, const float* __restrict__ fcw, int blk)
{
  constexpr int IN = (LAYER == 0) ? 34 : 136;   // non-recurrent input width
  constexpr int KS = (LAYER == 0) ? 4 : 7;      // K-steps of 32 (K = 128 / 224)
  constexpr int AW = (LAYER == 0) ? 136 : 232;  // A panel row stride (f16 elems)
  const int tid = threadIdx.x;
  const int ln = tid & 63;
  const int wid = tid >> 6;
  const int d = wid >> 2;        // 0 = fwd (waves 0-3), 1 = bwd (waves 4-7)
  const int wq = wid & 3;
  const int ut = tid & 255;      // lane id within direction group
  const int NT = (wq == 0) ? 5 : 4;                 // N-tiles owned (17 total)
  const int tbase = (wq == 0) ? 0 : (1 + wq * 4);   // w0:0-4 w1:5-8 w2:9-12 w3:13-16
  _Float16* Abuf = (LAYER == 0) ? &s.A0[d][0][0] : &s.A1[d][0][0];

  // ---- B fragments: held in registers for all 48 steps ----
  // B[k][n]: col n = lane%16, k = (lane/16)*8 + j.  k<IN -> Wih, k<IN+68 -> Whh, else 0.
  half8 Bf[5][KS];
  #pragma unroll
  for (int i = 0; i < 5; ++i) {
    if (i < NT) {
      const int g = (tbase + i) * 16 + (ln & 15);
      #pragma unroll
      for (int kk = 0; kk < KS; ++kk) {
        const int k0 = kk * 32 + (ln >> 4) * 8;
        half8 v;
        #pragma unroll
        for (int j = 0; j < 8; ++j) {
          const int k = k0 + j;
          float w = 0.f;
          if (k < IN) w = Wih[g * IN + k];
          else if (k < IN + 68) w = Whh[g * 68 + (k - IN)];
          v[j] = (_Float16)w;
        }
        Bf[i][kk] = v;
      }
    }
  }

  // ---- per-lane (b,j) ownership: p = j*8+b; lane owns p = ut, ut+256, ut+512(ut<32) ----
  const int jb = ut >> 3, bb = ut & 7;
  float bsI[3], bsF[3], bsG[3], bsO[3];
  #pragma unroll
  for (int q = 0; q < 3; ++q) {
    if (q < 2 || ut < 32) {
      const int j = jb + 32 * q;
      bsI[q] = bih[j] + bhh[j];
      bsF[q] = bih[68 + j] + bhh[68 + j];
      bsG[q] = bih[136 + j] + bhh[136 + j];
      bsO[q] = bih[204 + j] + bhh[204 + j];
    }
  }
  float cst[3] = {0.f, 0.f, 0.f};
  float yk[3][5];
  #pragma unroll
  for (int q = 0; q < 3; ++q)
    #pragma unroll
    for (int k = 0; k < 5; ++k) yk[q][k] = 0.f;

  const int t0 = d ? (TT - 1) : 0;

  // ---- prologue: stage step-0 inputs into the A panel ----
  if constexpr (LAYER == 0) {
    {
      const int b = ut / 34, i = ut % 34;
      s.A0[d][b][i] = (_Float16)x[((size_t)(blk * BT + b) * TT + t0) * 34 + i];
    }
    if (ut < 16) {
      const int e = ut + 256, b = e / 34, i = e % 34;
      s.A0[d][b][i] = (_Float16)x[((size_t)(blk * BT + b) * TT + t0) * 34 + i];
    }
  } else {
    if (ut < 136) {
      const int b = ut / 17, ch = ut % 17;
      *(uint4*)&s.A1[d][b][ch * 8] = *(const uint4*)&s.h0[t0][b][ch * 8];
    }
  }
  __syncthreads();

  #pragma unroll 1
  for (int st = 0; st < TT; ++st) {
    const int t = d ? (TT - 1 - st) : st;
    const int tn = d ? (t - 1) : (t + 1);

    // ---- issue prefetches: next-step x (L0) / this-step fcw slice (L1) ----
    float xpf0 = 0.f, xpf1 = 0.f;
    if constexpr (LAYER == 0) {
      if (st < TT - 1) {
        const int b = ut / 34, i = ut % 34;
        xpf0 = x[((size_t)(blk * BT + b) * TT + tn) * 34 + i];
        if (ut < 16) {
          const int e = ut + 256, b2 = e / 34, i2 = e % 34;
          xpf1 = x[((size_t)(blk * BT + b2) * TT + tn) * 34 + i2];
        }
      }
    }
    float fw[3][5];
    if constexpr (LAYER == 1) {
      #pragma unroll
      for (int q = 0; q < 3; ++q) {
        if (q < 2 || ut < 32) {
          const int j = jb + 32 * q;
          #pragma unroll
          for (int k = 0; k < 5; ++k)
            fw[q][k] = fcw[k * 6528 + t * 136 + d * 68 + j];
        }
      }
    }

    // ---- MFMA: gates = A(8xK) . B(Kx272) ----
    f32x4 acc[5];
    #pragma unroll
    for (int i = 0; i < 5; ++i) acc[i] = (f32x4){0.f, 0.f, 0.f, 0.f};
    const _Float16* Arow = Abuf + (ln & 15) * AW + (ln >> 4) * 8;
    #pragma unroll
    for (int kk = 0; kk < KS; ++kk) {
      const half8 a = *(const half8*)(Arow + kk * 32);
      #pragma unroll
      for (int i = 0; i < 5; ++i)
        if (i < NT)
          acc[i] = __builtin_amdgcn_mfma_f32_16x16x32_f16(a, Bf[i][kk], acc[i], 0, 0, 0);
    }
    // C/D: col = lane&15, row = (lane>>4)*4 + reg; rows 8-15 are padding
    if (ln < 32) {
      #pragma unroll
      for (int i = 0; i < 5; ++i)
        if (i < NT) {
          const int g = (tbase + i) * 16 + (ln & 15);
          #pragma unroll
          for (int r = 0; r < 4; ++r)
            s.gates[d][g][(ln >> 4) * 4 + r] = acc[i][r];
        }
    }
    __syncthreads();

    // ---- elementwise cell update (c stays in registers) ----
    #pragma unroll
    for (int q = 0; q < 3; ++q) {
      if (q < 2 || ut < 32) {
        const int j = jb + 32 * q;
        const float gi = s.gates[d][j][bb] + bsI[q];
        const float gf = s.gates[d][68 + j][bb] + bsF[q];
        const float gg = s.gates[d][136 + j][bb] + bsG[q];
        const float go = s.gates[d][204 + j][bb] + bsO[q];
        const float ii = sigm(gi), ff = sigm(gf), g2 = tanh_s(gg), oo = sigm(go);
        const float c = ff * cst[q] + ii * g2;
        cst[q] = c;
        const float h = oo * tanh_s(c);
        const _Float16 hh = (_Float16)h;
        if constexpr (LAYER == 0) {
          s.A0[d][bb][34 + j] = hh;
          s.h0[t][bb][d * 68 + j] = hh;
        } else {
          s.A1[d][bb][136 + j] = hh;
          #pragma unroll
          for (int k = 0; k < 5; ++k) yk[q][k] += h * fw[q][k];
        }
      }
    }
    // ---- stage next step's non-recurrent A part ----
    if constexpr (LAYER == 0) {
      if (st < TT - 1) {
        const int b = ut / 34, i = ut % 34;
        s.A0[d][b][i] = (_Float16)xpf0;
        if (ut < 16) {
          const int e = ut + 256, b2 = e / 34, i2 = e % 34;
          s.A0[d][b2][i2] = (_Float16)xpf1;
        }
      }
    } else {
      if (st < TT - 1 && ut < 136) {
        const int b = ut / 17, ch = ut % 17;
        *(uint4*)&s.A1[d][b][ch * 8] = *(const uint4*)&s.h0[tn][b][ch * 8];
      }
    }
    __syncthreads();
  }

  // ---- FC reduction: shuffle over jb within wave, partials to LDS ----
  if constexpr (LAYER == 1) {
    float ys[5];
    #pragma unroll
    for (int k = 0; k < 5; ++k) ys[k] = yk[0][k] + yk[1][k] + yk[2][k];
    #pragma unroll
    for (int m = 8; m <= 32; m <<= 1)
      #pragma unroll
      for (int k = 0; k < 5; ++k) ys[k] += __shfl_xor(ys[k], m, 64);
    if (ln < 8) {
      #pragma unroll
      for (int k = 0; k < 5; ++k) s.yred[wid][ln][k] = ys[k];
    }
  }
}

__global__ __attribute__((amdgpu_flat_work_group_size(NTHR, NTHR), amdgpu_waves_per_eu(2, 2)))
void lstm_fc_mfma(
    const float* __restrict__ x,
    const float* __restrict__ Wih0f, const float* __restrict__ Whh0f,
    const float* __restrict__ bih0f, const float* __restrict__ bhh0f,
    const float* __restrict__ Wih0b, const float* __restrict__ Whh0b,
    const float* __restrict__ bih0b, const float* __restrict__ bhh0b,
    const float* __restrict__ Wih1f, const float* __restrict__ Whh1f,
    const float* __restrict__ bih1f, const float* __restrict__ bhh1f,
    const float* __restrict__ Wih1b, const float* __restrict__ Whh1b,
    const float* __restrict__ bih1b, const float* __restrict__ bhh1b,
    const float* __restrict__ fcw, const float* __restrict__ fcb,
    float* __restrict__ out)
{
  extern __shared__ char smem_raw[];
  Smem& s = *reinterpret_cast<Smem*>(smem_raw);
  const int tid = threadIdx.x;
  const int blk = blockIdx.x;
  const int d = (tid >> 8) & 1;

  // zero the A panels (pad rows/cols must be 0 for MFMA)
  {
    int* z = (int*)&s.A0[0][0][0];
    const int n = (int)((sizeof(s.A0) + sizeof(s.A1)) / 4);
    for (int i = tid; i < n; i += NTHR) z[i] = 0;
  }
  __syncthreads();

  phase<0>(s, d ? Wih0b : Wih0f, d ? Whh0b : Whh0f,
              d ? bih0b : bih0f, d ? bhh0b : bhh0f, x, nullptr, blk);
  __syncthreads();
  phase<1>(s, d ? Wih1b : Wih1f, d ? Whh1b : Whh1f,
              d ? bih1b : bih1f, d ? bhh1b : bhh1f, nullptr, fcw, blk);
  __syncthreads();

  if (tid < BT * 5) {
    const int b = tid / 5, k = tid % 5;
    float v = fcb[k];
    #pragma unroll
    for (int w = 0; w < 8; ++w) v += s.yred[w][b][k];
    out[((size_t)blk * BT + b) * 5 + k] = v;
  }
}

extern "C" void kernel_launch(void* const* d_in, const int* in_sizes, int n_in,
                              void* d_out, int out_size, void* d_ws, size_t ws_size,
                              hipStream_t stream) {
  (void)in_sizes; (void)n_in; (void)d_ws; (void)ws_size; (void)out_size;
  static_assert(sizeof(Smem) <= 160 * 1024, "LDS overflow");
  hipFuncSetAttribute((const void*)lstm_fc_mfma,
                      hipFuncAttributeMaxDynamicSharedMemorySize, (int)sizeof(Smem));

  const float* x     = (const float*)d_in[0];
  const float* Wih0f = (const float*)d_in[1];
  const float* Whh0f = (const float*)d_in[2];
  const float* bih0f = (const float*)d_in[3];
  const float* bhh0f = (const float*)d_in[4];
  const float* Wih0b = (const float*)d_in[5];
  const float* Whh0b = (const float*)d_in[6];
  const float* bih0b = (const float*)d_in[7];
  const float* bhh0b = (const float*)d_in[8];
  const float* Wih1f = (const float*)d_in[9];
  const float* Whh1f = (const float*)d_in[10];
  const float* bih1f = (const float*)d_in[11];
  const float* bhh1f = (const float*)d_in[12];
  const float* Wih1b = (const float*)d_in[13];
  const float* Whh1b = (const float*)d_in[14];
  const float* bih1b = (const float*)d_in[15];
  const float* bhh1b = (const float*)d_in[16];
  const float* fcw   = (const float*)d_in[17];
  const float* fcb   = (const float*)d_in[18];
  float* out = (float*)d_out;

  lstm_fc_mfma<<<dim3(NBLK), dim3(NTHR), sizeof(Smem), stream>>>(x,
      Wih0f, Whh0f, bih0f, bhh0f, Wih0b, Whh0b, bih0b, bhh0b,
      Wih1f, Whh1f, bih1f, bhh1f, Wih1b, Whh1b, bih1b, bhh1b,
      fcw, fcb, out);
}